// Round 4
// baseline (450.142 us; speedup 1.0000x reference)
//
#include <hip/hip_runtime.h>
#include <math.h>

#define B 4096
#define C 5
#define NNEG 20
#define D 128
#define NROWS (C + C * NNEG)   // 105 rows per batch element
#define NEMB 400000
#define CAP 8                  // bucket slots per emb row (P(>8 refs) ~ 1e-6/row)
#define OVF_MAX 8192
#define RPB 200                // rows per k3 block
#define SBLK (NEMB / RPB)      // 2000 blocks
#define NIT (RPB / 8)          // 25 rows per half-wave

typedef unsigned int uint32;

// ---------------- workspace layout (bytes) ----------------
#define OFF_V1     ((size_t)0)                         // B*D floats      = 2,097,152
#define OFF_SCORE  (OFF_V1 + (size_t)B * D * 4)        // B*NROWS floats  = 1,720,320
#define OFF_PART   (OFF_SCORE + (size_t)B * NROWS * 4) // B floats
#define OFF_CNT    (OFF_PART + (size_t)B * 4)          // NEMB u32
#define OFF_OVFC   (OFF_CNT + (size_t)NEMB * 4)        // 1 u32 (+pad to 64)
#define OFF_OVF    (OFF_OVFC + 64)                     // 2*OVF_MAX u32 (row,pair flat)
#define OFF_BUCKET (OFF_OVF + (size_t)OVF_MAX * 8)     // NEMB*CAP u32 = 12,800,000
#define WS_NEED    (OFF_BUCKET + (size_t)NEMB * CAP * 4)   // ~18.3 MB

// stable log sigmoid: logsig(x) = min(x,0) - log1p(exp(-|x|))
__device__ __forceinline__ float log_sigmoid(float x) {
    return fminf(x, 0.0f) - log1pf(__expf(-fabsf(x)));
}

// 32-lane dot over D=128 (lane l32 owns dims 4*l32..4*l32+3); result uniform
// within each 32-lane half-wave. Identical op order to the verified kernel.
__device__ __forceinline__ float dot_butterfly(float4 vf, float4 rv) {
    float t = vf.x * rv.x + vf.y * rv.y + vf.z * rv.z + vf.w * rv.w;
    t += __shfl_xor(t, 1, 64);
    t += __shfl_xor(t, 2, 64);
    t += __shfl_xor(t, 4, 64);
    t += __shfl_xor(t, 8, 64);
    t += __shfl_xor(t, 16, 64);
    return t;
}

// ---- kA: zero counters AND stage center vectors (fused; both finish before k2/k3) ----
__global__ __launch_bounds__(256) void kA_init(const int* __restrict__ iword,
                                               const float* __restrict__ emb1,
                                               float* __restrict__ v1s,
                                               uint32* __restrict__ cnt,
                                               uint32* __restrict__ ovfc) {
    const int g = blockIdx.x * 256 + threadIdx.x;     // grid = 512 blocks
    for (int i = g; i < NEMB; i += 512 * 256) cnt[i] = 0;
    if (g == 0) *ovfc = 0;

    const int hw = threadIdx.x >> 5, l32 = threadIdx.x & 31;
    const int b = blockIdx.x * 8 + hw;                // 512*8 = 4096 = B
    int ci = iword[b];
    if ((unsigned)ci >= NEMB) ci = 0;                 // defensive clamp
    const float4 v = ((const float4*)(emb1 + (long)ci * D))[l32];
    ((float4*)(v1s + (long)b * D))[l32] = v;
}

// ---- k2: bucket every (row -> (b,slot)) reference by emb2 row index ----
__global__ __launch_bounds__(128) void k2_scatter(const int* __restrict__ ow,
                                                  const int* __restrict__ nw,
                                                  uint32* __restrict__ cnt,
                                                  uint32* __restrict__ bucket,
                                                  uint32* __restrict__ ovfc,
                                                  uint32* __restrict__ ovf) {
    const int b = blockIdx.x;        // grid = B
    const int r = threadIdx.x;
    if (r >= NROWS) return;
    int row = (r < C) ? ow[b * C + r] : nw[b * (C * NNEG) + (r - C)];
    if ((unsigned)row >= NEMB) row = 0;               // defensive clamp
    const uint32 pair = ((uint32)b << 7) | (uint32)r; // b:12 bits, r:7 bits
    const uint32 c = atomicAdd(&cnt[row], 1u);
    if (c < CAP) {
        bucket[(long)row * CAP + c] = pair;
    } else {
        const uint32 o = atomicAdd(ovfc, 1u);
        if (o < OVF_MAX) { ovf[2 * o] = (uint32)row; ovf[2 * o + 1] = pair; }
    }
}

// ---- k3: sweep emb2 in ASCENDING row order (page-coherent DRAM streaming),
//          computing dots for referenced rows. Depth-2 branchless pipeline:
//          row i+1's {rv, cnt, bucket-word} loads are in flight while row i
//          is processed. Block 0 additionally drains the overflow list. ----
__global__ __launch_bounds__(256) void k3_stream(const float* __restrict__ emb2,
                                                 const float* __restrict__ v1s,
                                                 const uint32* __restrict__ cnt,
                                                 const uint32* __restrict__ bucket,
                                                 const uint32* __restrict__ ovfc,
                                                 const uint32* __restrict__ ovf,
                                                 float* __restrict__ score) {
    const int tid = threadIdx.x;
    const int hw = tid >> 5, l32 = tid & 31;
    const int rbase = blockIdx.x * RPB;

    int    row_c = rbase + hw;
    float4 rv_c  = ((const float4*)(emb2 + (long)row_c * D))[l32];
    uint32 n_c   = cnt[row_c];
    uint32 bw_c  = bucket[(long)row_c * CAP + (l32 & 7)];

    #pragma unroll 1
    for (int i = 0; i < NIT; ++i) {
        // prefetch next row (branchless; tail re-loads current row harmlessly)
        const int row_n = (i + 1 < NIT) ? (row_c + 8) : row_c;
        const float4 rv_n = ((const float4*)(emb2 + (long)row_n * D))[l32];
        const uint32 n_n  = cnt[row_n];
        const uint32 bw_n = bucket[(long)row_n * CAP + (l32 & 7)];

        if (n_c) {
            uint32 n = n_c > CAP ? CAP : n_c;
            for (uint32 k = 0; k < n; ++k) {
                const uint32 pair = __shfl(bw_c, (int)k, 32); // lane k of this half
                const int bb = (int)(pair >> 7);
                const int rr = (int)(pair & 127);
                const float4 vf = ((const float4*)(v1s + (long)bb * D))[l32];
                const float t = dot_butterfly(vf, rv_c);
                if (l32 == 0 && bb < B && rr < NROWS) score[bb * NROWS + rr] = t;
            }
        }
        row_c = row_n; rv_c = rv_n; n_c = n_n; bw_c = bw_n;
    }

    // overflow drain (rare; exact) — refs here were NOT bucketed, so no write race
    if (blockIdx.x == 0) {
        uint32 m = *ovfc;
        if (m > OVF_MAX) m = OVF_MAX;
        for (uint32 e = hw; e < m; e += 8) {
            uint32 row = ovf[2 * e];
            const uint32 pair = ovf[2 * e + 1];
            if (row >= NEMB) continue;
            const int bb = (int)(pair >> 7);
            const int rr = (int)(pair & 127);
            const float4 rv = ((const float4*)(emb2 + (long)row * D))[l32];
            const float4 vf = ((const float4*)(v1s + (long)bb * D))[l32];
            const float t = dot_butterfly(vf, rv);
            if (l32 == 0 && bb < B && rr < NROWS) score[bb * NROWS + rr] = t;
        }
    }
}

// ---- k5: per-b finish — reduction tree identical to the verified gather kernel ----
__global__ __launch_bounds__(256) void k5_finish(const float* __restrict__ score,
                                                 float* __restrict__ partial) {
    const int b = blockIdx.x;
    const int tid = threadIdx.x;
    const int lane = tid & 63, wave = tid >> 6, hw = tid >> 5;

    float acc = 0.0f;
    #pragma unroll
    for (int s = 0; s < 14; ++s) {
        const int r = s * 8 + hw;
        const bool valid = (r < NROWS);
        const int rr = valid ? r : 0;
        const float sgn = (rr < C) ? 1.0f : -1.0f;
        const float t = score[b * NROWS + rr];
        const float v = log_sigmoid(sgn * t);
        acc += valid ? v : 0.0f;
    }
    acc += __shfl_xor(acc, 32, 64);

    __shared__ float wsum[4];
    if (lane == 0) wsum[wave] = acc;
    __syncthreads();
    if (tid == 0)
        partial[b] = wsum[0] + wsum[1] + wsum[2] + wsum[3];
}

// ---- k6: final scalar ----
__global__ __launch_bounds__(256) void sgns_reduce(const float* __restrict__ partial,
                                                   float* __restrict__ out) {
    const int tid = threadIdx.x;
    float acc = 0.0f;
    for (int i = tid; i < B; i += 256) acc += partial[i];
    #pragma unroll
    for (int off = 32; off > 0; off >>= 1)
        acc += __shfl_xor(acc, off, 64);
    __shared__ float ws[4];
    if ((tid & 63) == 0) ws[tid >> 6] = acc;
    __syncthreads();
    if (tid == 0) out[0] = -(ws[0] + ws[1] + ws[2] + ws[3]) / (float)(B * C);
}

// ---- fallback (ws too small): the round-2 verified gather kernel ----
__global__ __launch_bounds__(256) void sgns_partial_gather(
    const int* __restrict__ iword, const int* __restrict__ owords,
    const int* __restrict__ nwords, const float* __restrict__ emb1,
    const float* __restrict__ emb2, float* __restrict__ partial)
{
    const int b = blockIdx.x, tid = threadIdx.x;
    const int lane = tid & 63, wave = tid >> 6, hw = tid >> 5, l32 = tid & 31;
    const float4 v1f = ((const float4*)(emb1 + (long)iword[b] * D))[l32];
    float acc = 0.0f;
    #pragma unroll
    for (int s = 0; s < 14; ++s) {
        const int r = s * 8 + hw;
        const bool valid = (r < NROWS);
        const int rr = valid ? r : 0;
        const bool pos = (rr < C);
        const int idx = pos ? owords[b * C + rr] : nwords[b * (C * NNEG) + (rr - C)];
        const float4 rv = ((const float4*)(emb2 + (long)idx * D))[l32];
        const float t = dot_butterfly(v1f, rv);
        const float v = log_sigmoid((pos ? 1.0f : -1.0f) * t);
        acc += valid ? v : 0.0f;
    }
    acc += __shfl_xor(acc, 32, 64);
    __shared__ float wsum[4];
    if (lane == 0) wsum[wave] = acc;
    __syncthreads();
    if (tid == 0) partial[b] = wsum[0] + wsum[1] + wsum[2] + wsum[3];
}

extern "C" void kernel_launch(void* const* d_in, const int* in_sizes, int n_in,
                              void* d_out, int out_size, void* d_ws, size_t ws_size,
                              hipStream_t stream) {
    const int*   iword  = (const int*)d_in[0];
    const int*   owords = (const int*)d_in[1];
    const int*   nwords = (const int*)d_in[2];
    const float* emb1   = (const float*)d_in[3];
    const float* emb2   = (const float*)d_in[4];
    float* out = (float*)d_out;

    char* ws = (char*)d_ws;
    float*  v1s     = (float*)(ws + OFF_V1);
    float*  score   = (float*)(ws + OFF_SCORE);
    float*  partial = (float*)(ws + OFF_PART);
    uint32* cnt     = (uint32*)(ws + OFF_CNT);
    uint32* ovfc    = (uint32*)(ws + OFF_OVFC);
    uint32* ovf     = (uint32*)(ws + OFF_OVF);
    uint32* bucket  = (uint32*)(ws + OFF_BUCKET);

    if (ws_size >= WS_NEED) {
        kA_init   <<<512, 256, 0, stream>>>(iword, emb1, v1s, cnt, ovfc);
        k2_scatter<<<B, 128, 0, stream>>>(owords, nwords, cnt, bucket, ovfc, ovf);
        k3_stream <<<SBLK, 256, 0, stream>>>(emb2, v1s, cnt, bucket, ovfc, ovf, score);
        k5_finish <<<B, 256, 0, stream>>>(score, partial);
        sgns_reduce<<<1, 256, 0, stream>>>(partial, out);
    } else {
        float* part2 = (float*)d_ws;   // B floats
        sgns_partial_gather<<<B, 256, 0, stream>>>(iword, owords, nwords, emb1, emb2, part2);
        sgns_reduce<<<1, 256, 0, stream>>>(part2, out);
    }
}

// Round 5
// 356.152 us; speedup vs baseline: 1.2639x; 1.2639x over previous
//
#include <hip/hip_runtime.h>
#include <math.h>

#define B 4096
#define C 5
#define NNEG 20
#define D 128
#define NROWS (C + C * NNEG)  // 105 rows per batch element (5 pos + 100 neg)

// stable log sigmoid: logsig(x) = min(x,0) - log1p(exp(-|x|))
__device__ __forceinline__ float log_sigmoid(float x) {
    return fminf(x, 0.0f) - log1pf(__expf(-fabsf(x)));
}

// One block per batch element b. 256 threads = 4 waves = 32 row-groups.
// Each 8-lane group owns row slots base, base+32, base+64, base+96.
// Structure: load 4 indices -> issue ALL 16 float4 row loads (prefetch,
// 16KB/wave outstanding) -> 4x {dot, 3-shuffle group butterfly, logsig}.
// Invalid tail slots (row >= 105) are clamped to index 0 (L1-hit dummy load)
// and masked out of the accumulation -> no divergent guards around loads.
//
// ROOFLINE NOTE (rounds 0-4 evidence): this kernel runs ~110 us, moving
// ~140 MB of compulsory cold random 512B rows at ~1.3 TB/s — within ~10%
// of the DRAM row-activate (tRC) ceiling for random gathers. Neutral
// results from: request-count reduction (r1), persistent pipelining (r1),
// 512B-contiguous requests (r2); full gather->stream inversion regressed
// (r4, +95 us). Remaining dur_us is harness poison fills (2 x ~120 us at
// 85% HBM peak) + 3 us reduce.
__global__ __launch_bounds__(256) void sgns_partial(
    const int* __restrict__ iword,
    const int* __restrict__ owords,
    const int* __restrict__ nwords,
    const float* __restrict__ emb1,
    const float* __restrict__ emb2,
    float* __restrict__ partial)
{
    const int b    = blockIdx.x;
    const int tid  = threadIdx.x;
    const int lane = tid & 63;
    const int wave = tid >> 6;       // 0..3
    const int grp  = lane >> 3;      // 0..7
    const int j    = lane & 7;       // dim-slice owner within group
    const int base = wave * 8 + grp; // 0..31

    // v1 fragment: dims 4j+32k, k=0..3 (16 floats in registers)
    const long center = (long)iword[b] * D;
    const float4* v1p = (const float4*)(emb1 + center);
    float4 v1f[4];
    #pragma unroll
    for (int k = 0; k < 4; ++k) v1f[k] = v1p[j + 8 * k];

    // resolve the 4 row indices (clamp invalid tail slots to row-slot 0)
    int   rIdx[4];
    float sgn[4];
    bool  valid[4];
    #pragma unroll
    for (int p = 0; p < 4; ++p) {
        const int r = base + 32 * p;
        valid[p] = (r < NROWS);
        const int rr = valid[p] ? r : 0;
        const bool pos = (rr < C);
        sgn[p] = pos ? 1.0f : -1.0f;
        rIdx[p] = pos ? owords[b * C + rr]
                      : nwords[b * (C * NNEG) + (rr - C)];
    }

    // prefetch all 16 float4s (4 rows x 4 slices) before consuming any
    float4 rw[4][4];
    #pragma unroll
    for (int p = 0; p < 4; ++p) {
        const float4* rp = (const float4*)(emb2 + (long)rIdx[p] * D);
        #pragma unroll
        for (int k = 0; k < 4; ++k) rw[p][k] = rp[j + 8 * k];
    }

    float acc = 0.0f;
    #pragma unroll
    for (int p = 0; p < 4; ++p) {
        float s = 0.0f;
        #pragma unroll
        for (int k = 0; k < 4; ++k) {
            s += v1f[k].x * rw[p][k].x + v1f[k].y * rw[p][k].y
               + v1f[k].z * rw[p][k].z + v1f[k].w * rw[p][k].w;
        }
        // 3-step butterfly within the 8-lane group
        s += __shfl_xor(s, 1, 64);
        s += __shfl_xor(s, 2, 64);
        s += __shfl_xor(s, 4, 64);

        const float v = log_sigmoid(sgn[p] * s);
        acc += valid[p] ? v : 0.0f;
    }

    // acc is uniform within each 8-lane group -> reduce across groups only
    acc += __shfl_xor(acc, 8, 64);
    acc += __shfl_xor(acc, 16, 64);
    acc += __shfl_xor(acc, 32, 64);
    // every lane now holds the wave's total (each row counted exactly once)

    __shared__ float wsum[4];
    if (lane == 0) wsum[wave] = acc;
    __syncthreads();
    if (tid == 0)
        partial[b] = wsum[0] + wsum[1] + wsum[2] + wsum[3];
}

// Single-block final reduction: out = -(sum of all logsig terms) / (B*C)
__global__ __launch_bounds__(256) void sgns_reduce(
    const float* __restrict__ partial,
    float* __restrict__ out)
{
    const int tid = threadIdx.x;
    float acc = 0.0f;
    for (int i = tid; i < B; i += 256) acc += partial[i];

    #pragma unroll
    for (int off = 32; off > 0; off >>= 1)
        acc += __shfl_xor(acc, off, 64);

    __shared__ float ws[4];
    if ((tid & 63) == 0) ws[tid >> 6] = acc;
    __syncthreads();
    if (tid == 0) out[0] = -(ws[0] + ws[1] + ws[2] + ws[3]) / (float)(B * C);
}

extern "C" void kernel_launch(void* const* d_in, const int* in_sizes, int n_in,
                              void* d_out, int out_size, void* d_ws, size_t ws_size,
                              hipStream_t stream) {
    const int*   iword  = (const int*)d_in[0];
    const int*   owords = (const int*)d_in[1];
    const int*   nwords = (const int*)d_in[2];
    const float* emb1   = (const float*)d_in[3];
    const float* emb2   = (const float*)d_in[4];
    float* out     = (float*)d_out;
    float* partial = (float*)d_ws;  // B floats = 16 KB

    sgns_partial<<<B, 256, 0, stream>>>(iword, owords, nwords, emb1, emb2, partial);
    sgns_reduce<<<1, 256, 0, stream>>>(partial, out);
}